// Round 4
// baseline (534.246 us; speedup 1.0000x reference)
//
#include <hip/hip_runtime.h>

// ReactionTerm: y_out[b, inds_1p[r]] += y_in[b, inds_1r[r]] * rates_1st[b, r]
//               y_out[b, inds_2p[r]] += y_in[b, i2r0[r]] * y_in[b, i2r1[r]] * rates_2nd[b, r]
// B=1024, N_SPEC=2048, R1=20000, R2=40000.
//
// R1-R3 post-mortem: 332-340 us invariant across ILP/occupancy/atomic changes;
// ~3.4k cycles per wave-iteration, all pipes <6% busy -> fixed serialized cost
// per iteration, and >half of per-block global traffic is the index stream
// re-read identically by every block.
// This round: G=4 batch rows per block. One index load feeds 4 rows of work
// (4x fewer iterations, 4x less index traffic). LDS 64KB/block, BLOCK=1024,
// grid=256.

#define B_DIM 1024
#define N_SPEC 2048
#define R1 20000
#define R2 40000
#define G 4
#define BLOCK 1024
#define GRID (B_DIM / G)   // 256 blocks
#define P1 (R1 / 4)        // 5000 packs
#define P2 (R2 / 4)        // 10000 packs

__global__ __launch_bounds__(BLOCK, 4) void ReactionTerm_kernel(
    const float* __restrict__ y_in,       // [B, N_SPEC]
    const float* __restrict__ rates_1st,  // [B, R1]
    const float* __restrict__ rates_2nd,  // [B, R2]
    const int*   __restrict__ inds_1r,    // [R1]
    const int*   __restrict__ inds_1p,    // [R1]
    const int*   __restrict__ inds_2r,    // [R2, 2]
    const int*   __restrict__ inds_2p,    // [R2]
    float*       __restrict__ y_out)      // [B, N_SPEC]
{
    __shared__ float ys[G * N_SPEC];  // 32 KB staged input rows
    __shared__ float yo[G * N_SPEC];  // 32 KB accumulator rows

    const int b0  = blockIdx.x * G;
    const int tid = threadIdx.x;

    // Stage G contiguous rows (32 KB) and zero the accumulator.
    const float4* yrow = reinterpret_cast<const float4*>(y_in + (size_t)b0 * N_SPEC);
    float4* ys4 = reinterpret_cast<float4*>(ys);
    float4* yo4 = reinterpret_cast<float4*>(yo);
    #pragma unroll
    for (int i = tid; i < G * N_SPEC / 4; i += BLOCK) {
        ys4[i] = yrow[i];
        yo4[i] = make_float4(0.f, 0.f, 0.f, 0.f);
    }
    __syncthreads();

    // ---- First-order: one index pack drives 4 rows. ----
    {
        const int4*   i1r4 = reinterpret_cast<const int4*>(inds_1r);
        const int4*   i1p4 = reinterpret_cast<const int4*>(inds_1p);
        const float4* q0p = reinterpret_cast<const float4*>(rates_1st + (size_t)(b0 + 0) * R1);
        const float4* q1p = reinterpret_cast<const float4*>(rates_1st + (size_t)(b0 + 1) * R1);
        const float4* q2p = reinterpret_cast<const float4*>(rates_1st + (size_t)(b0 + 2) * R1);
        const float4* q3p = reinterpret_cast<const float4*>(rates_1st + (size_t)(b0 + 3) * R1);
        for (int v = tid; v < P1; v += BLOCK) {
            const int4   ir = i1r4[v];
            const int4   ip = i1p4[v];
            const float4 q0 = q0p[v];
            const float4 q1 = q1p[v];
            const float4 q2 = q2p[v];
            const float4 q3 = q3p[v];
            const float a0 = ys[0 * N_SPEC + ir.x], a1 = ys[0 * N_SPEC + ir.y],
                        a2 = ys[0 * N_SPEC + ir.z], a3 = ys[0 * N_SPEC + ir.w];
            const float b1_ = ys[1 * N_SPEC + ir.x], b2_ = ys[1 * N_SPEC + ir.y],
                        b3_ = ys[1 * N_SPEC + ir.z], b4_ = ys[1 * N_SPEC + ir.w];
            const float c0 = ys[2 * N_SPEC + ir.x], c1 = ys[2 * N_SPEC + ir.y],
                        c2 = ys[2 * N_SPEC + ir.z], c3 = ys[2 * N_SPEC + ir.w];
            const float d0 = ys[3 * N_SPEC + ir.x], d1 = ys[3 * N_SPEC + ir.y],
                        d2 = ys[3 * N_SPEC + ir.z], d3 = ys[3 * N_SPEC + ir.w];
            unsafeAtomicAdd(&yo[0 * N_SPEC + ip.x], a0 * q0.x);
            unsafeAtomicAdd(&yo[0 * N_SPEC + ip.y], a1 * q0.y);
            unsafeAtomicAdd(&yo[0 * N_SPEC + ip.z], a2 * q0.z);
            unsafeAtomicAdd(&yo[0 * N_SPEC + ip.w], a3 * q0.w);
            unsafeAtomicAdd(&yo[1 * N_SPEC + ip.x], b1_ * q1.x);
            unsafeAtomicAdd(&yo[1 * N_SPEC + ip.y], b2_ * q1.y);
            unsafeAtomicAdd(&yo[1 * N_SPEC + ip.z], b3_ * q1.z);
            unsafeAtomicAdd(&yo[1 * N_SPEC + ip.w], b4_ * q1.w);
            unsafeAtomicAdd(&yo[2 * N_SPEC + ip.x], c0 * q2.x);
            unsafeAtomicAdd(&yo[2 * N_SPEC + ip.y], c1 * q2.y);
            unsafeAtomicAdd(&yo[2 * N_SPEC + ip.z], c2 * q2.z);
            unsafeAtomicAdd(&yo[2 * N_SPEC + ip.w], c3 * q2.w);
            unsafeAtomicAdd(&yo[3 * N_SPEC + ip.x], d0 * q3.x);
            unsafeAtomicAdd(&yo[3 * N_SPEC + ip.y], d1 * q3.y);
            unsafeAtomicAdd(&yo[3 * N_SPEC + ip.z], d2 * q3.z);
            unsafeAtomicAdd(&yo[3 * N_SPEC + ip.w], d3 * q3.w);
        }
    }

    // ---- Second-order: one index pack drives 4 rows. ----
    {
        const int4*   i2r4 = reinterpret_cast<const int4*>(inds_2r);  // int4 = 2 reactions
        const int4*   i2p4 = reinterpret_cast<const int4*>(inds_2p);
        const float4* q0p = reinterpret_cast<const float4*>(rates_2nd + (size_t)(b0 + 0) * R2);
        const float4* q1p = reinterpret_cast<const float4*>(rates_2nd + (size_t)(b0 + 1) * R2);
        const float4* q2p = reinterpret_cast<const float4*>(rates_2nd + (size_t)(b0 + 2) * R2);
        const float4* q3p = reinterpret_cast<const float4*>(rates_2nd + (size_t)(b0 + 3) * R2);
        for (int v = tid; v < P2; v += BLOCK) {
            const int4   ra = i2r4[2 * v];      // reactions 4v, 4v+1
            const int4   rb = i2r4[2 * v + 1];  // reactions 4v+2, 4v+3
            const int4   ip = i2p4[v];
            const float4 q0 = q0p[v];
            const float4 q1 = q1p[v];
            const float4 q2 = q2p[v];
            const float4 q3 = q3p[v];
            #pragma unroll
            for (int g = 0; g < G; ++g) {
                const float* ysg = ys + g * N_SPEC;
                float*       yog = yo + g * N_SPEC;
                const float4 q = (g == 0) ? q0 : (g == 1) ? q1 : (g == 2) ? q2 : q3;
                const float t0 = ysg[ra.x] * ysg[ra.y] * q.x;
                const float t1 = ysg[ra.z] * ysg[ra.w] * q.y;
                const float t2 = ysg[rb.x] * ysg[rb.y] * q.z;
                const float t3 = ysg[rb.z] * ysg[rb.w] * q.w;
                unsafeAtomicAdd(&yog[ip.x], t0);
                unsafeAtomicAdd(&yog[ip.y], t1);
                unsafeAtomicAdd(&yog[ip.z], t2);
                unsafeAtomicAdd(&yog[ip.w], t3);
            }
        }
    }
    __syncthreads();

    // Write back G contiguous rows (32 KB).
    float4* orow = reinterpret_cast<float4*>(y_out + (size_t)b0 * N_SPEC);
    #pragma unroll
    for (int i = tid; i < G * N_SPEC / 4; i += BLOCK) {
        orow[i] = yo4[i];
    }
}

extern "C" void kernel_launch(void* const* d_in, const int* in_sizes, int n_in,
                              void* d_out, int out_size, void* d_ws, size_t ws_size,
                              hipStream_t stream) {
    const float* y_in      = (const float*)d_in[0];
    const float* rates_1st = (const float*)d_in[1];
    const float* rates_2nd = (const float*)d_in[2];
    const int*   inds_1r   = (const int*)d_in[3];
    const int*   inds_1p   = (const int*)d_in[4];
    const int*   inds_2r   = (const int*)d_in[5];
    const int*   inds_2p   = (const int*)d_in[6];
    float*       y_out     = (float*)d_out;

    ReactionTerm_kernel<<<GRID, BLOCK, 0, stream>>>(
        y_in, rates_1st, rates_2nd, inds_1r, inds_1p, inds_2r, inds_2p, y_out);
}

// Round 5
// 402.250 us; speedup vs baseline: 1.3281x; 1.3281x over previous
//
#include <hip/hip_runtime.h>

// ReactionTerm: y_out[b, inds_1p[r]] += y_in[b, inds_1r[r]] * rates_1st[b, r]
//               y_out[b, inds_2p[r]] += y_in[b, i2r0[r]] * y_in[b, i2r1[r]] * rates_2nd[b, r]
// B=1024, N_SPEC=2048, R1=20000, R2=40000.
//
// R1-R4 post-mortem: 332-340 us invariant across occupancy/ILP/prefetch/index
// dedup; ~210 cyc/CU per wave-level ds_add_f32 is the invariant -> LDS atomic
// RMW path is the serial resource. This round: ZERO atomics in the hot path.
// Per launch, setup kernels build a product-sorted (CSR) reaction list in d_ws,
// chunked by 10000 reactions so each chunk's rates row fits in LDS. Main
// kernel: 1 block/row, thread owns 4 species, accumulates in REGISTERS; LDS is
// read-only (y gathers + staged-rate gathers); rates stream coalesced.

#define NSPEC 2048
#define BDIM  1024
#define R1    20000
#define R2    40000
#define CH    10000         // reactions per chunk
#define NCH1  2             // first-order chunks
#define NCH2  4             // second-order chunks
#define NCH   (NCH1 + NCH2)
#define RTOT  (R1 + R2)

// d_ws layout (bytes):
#define WS_CNT  0                         // uint[NCH*NSPEC]      = 49152 B (doubles as fill cursor)
#define WS_PTR  49152                     // uint[NCH*(NSPEC+1)]  = 49176 B
#define WS_E1   98432                     // uint[R1]             = 80000 B  (reactant | local_j<<16)
#define WS_E2   178560                    // uint2[R2]            = 320000 B (r0|r1<<16, local_j)

__global__ __launch_bounds__(256) void k_zero(uint* cnt) {
    int i = blockIdx.x * 256 + threadIdx.x;
    if (i < NCH * NSPEC) cnt[i] = 0u;
}

__global__ __launch_bounds__(256) void k_hist(const int* __restrict__ inds_1p,
                                              const int* __restrict__ inds_2p,
                                              uint* __restrict__ cnt) {
    int j = blockIdx.x * 256 + threadIdx.x;
    if (j >= RTOT) return;
    if (j < R1) {
        int c = j / CH;
        atomicAdd(&cnt[c * NSPEC + inds_1p[j]], 1u);
    } else {
        int j2 = j - R1;
        int c = NCH1 + j2 / CH;
        atomicAdd(&cnt[c * NSPEC + inds_2p[j2]], 1u);
    }
}

// One block per chunk: exclusive scan of 2048 counts -> ptr; reset cnt=ptr (cursor).
__global__ __launch_bounds__(256) void k_scan(uint* __restrict__ cnt,
                                              uint* __restrict__ ptr) {
    __shared__ uint part[256];
    const int c   = blockIdx.x;
    const int tid = threadIdx.x;
    uint v[8];
    uint tsum = 0;
    #pragma unroll
    for (int k = 0; k < 8; ++k) { v[k] = cnt[c * NSPEC + tid * 8 + k]; tsum += v[k]; }
    part[tid] = tsum;
    __syncthreads();
    // Hillis-Steele inclusive scan over 256 partials.
    for (int off = 1; off < 256; off <<= 1) {
        uint x = (tid >= off) ? part[tid - off] : 0u;
        __syncthreads();
        part[tid] += x;
        __syncthreads();
    }
    uint run = part[tid] - tsum;   // exclusive prefix of this thread's 8
    #pragma unroll
    for (int k = 0; k < 8; ++k) {
        ptr[c * (NSPEC + 1) + tid * 8 + k] = run;
        cnt[c * NSPEC + tid * 8 + k]       = run;   // cursor for fill
        run += v[k];
    }
    if (tid == 255) ptr[c * (NSPEC + 1) + NSPEC] = run;
}

__global__ __launch_bounds__(256) void k_fill(const int* __restrict__ inds_1r,
                                              const int* __restrict__ inds_1p,
                                              const int* __restrict__ inds_2r,
                                              const int* __restrict__ inds_2p,
                                              uint*  __restrict__ cur,
                                              uint*  __restrict__ e1,
                                              uint2* __restrict__ e2) {
    int j = blockIdx.x * 256 + threadIdx.x;
    if (j >= RTOT) return;
    if (j < R1) {
        int c = j / CH;
        int s = inds_1p[j];
        uint pos = atomicAdd(&cur[c * NSPEC + s], 1u);
        uint jl  = (uint)(j - c * CH);
        e1[c * CH + pos] = (uint)inds_1r[j] | (jl << 16);
    } else {
        int j2 = j - R1;
        int c  = j2 / CH;
        int s  = inds_2p[j2];
        uint pos = atomicAdd(&cur[(NCH1 + c) * NSPEC + s], 1u);
        uint jl  = (uint)(j2 - c * CH);
        uint r0  = (uint)inds_2r[2 * j2];
        uint r1_ = (uint)inds_2r[2 * j2 + 1];
        e2[c * CH + pos] = make_uint2(r0 | (r1_ << 16), jl);
    }
}

#define MBLOCK 512
#define SPT    (NSPEC / MBLOCK)   // 4 species per thread

__global__ __launch_bounds__(MBLOCK) void k_main(
    const float* __restrict__ y_in,
    const float* __restrict__ rates_1st,
    const float* __restrict__ rates_2nd,
    const uint*  __restrict__ ptr,
    const uint*  __restrict__ e1,
    const uint2* __restrict__ e2,
    float*       __restrict__ y_out)
{
    __shared__ float ys[NSPEC];   // 8 KB input row
    __shared__ float rl[CH];      // 40 KB staged rates chunk

    const int b   = blockIdx.x;
    const int tid = threadIdx.x;

    // Stage y row (512 float4 = one per thread).
    {
        const float4* yrow = reinterpret_cast<const float4*>(y_in + (size_t)b * NSPEC);
        reinterpret_cast<float4*>(ys)[tid] = yrow[tid];
    }

    float acc[SPT];
    #pragma unroll
    for (int k = 0; k < SPT; ++k) acc[k] = 0.f;

    for (int c = 0; c < NCH; ++c) {
        // Stage this chunk's rates row (coalesced float4 stream).
        const float* src = (c < NCH1)
            ? rates_1st + (size_t)b * R1 + c * CH
            : rates_2nd + (size_t)b * R2 + (c - NCH1) * CH;
        const float4* src4 = reinterpret_cast<const float4*>(src);
        float4* rl4 = reinterpret_cast<float4*>(rl);
        #pragma unroll
        for (int i = tid; i < CH / 4; i += MBLOCK) rl4[i] = src4[i];
        __syncthreads();

        const uint* pb = ptr + c * (NSPEC + 1);
        if (c < NCH1) {
            const uint* ec = e1 + c * CH;
            #pragma unroll
            for (int k = 0; k < SPT; ++k) {
                const int s = tid + k * MBLOCK;
                const uint beg = pb[s], end = pb[s + 1];
                float a = 0.f;
                for (uint j = beg; j < end; ++j) {
                    const uint e = ec[j];
                    a += ys[e & 0xFFFFu] * rl[e >> 16];
                }
                acc[k] += a;
            }
        } else {
            const uint2* ec = e2 + (c - NCH1) * CH;
            #pragma unroll
            for (int k = 0; k < SPT; ++k) {
                const int s = tid + k * MBLOCK;
                const uint beg = pb[s], end = pb[s + 1];
                float a = 0.f;
                for (uint j = beg; j < end; ++j) {
                    const uint2 e = ec[j];
                    a += ys[e.x & 0xFFFFu] * ys[e.x >> 16] * rl[e.y];
                }
                acc[k] += a;
            }
        }
        __syncthreads();   // before next chunk overwrites rl
    }

    // Coalesced writeback: thread tid owns species tid + k*MBLOCK.
    #pragma unroll
    for (int k = 0; k < SPT; ++k)
        y_out[(size_t)b * NSPEC + tid + k * MBLOCK] = acc[k];
}

extern "C" void kernel_launch(void* const* d_in, const int* in_sizes, int n_in,
                              void* d_out, int out_size, void* d_ws, size_t ws_size,
                              hipStream_t stream) {
    const float* y_in      = (const float*)d_in[0];
    const float* rates_1st = (const float*)d_in[1];
    const float* rates_2nd = (const float*)d_in[2];
    const int*   inds_1r   = (const int*)d_in[3];
    const int*   inds_1p   = (const int*)d_in[4];
    const int*   inds_2r   = (const int*)d_in[5];
    const int*   inds_2p   = (const int*)d_in[6];
    float*       y_out     = (float*)d_out;

    char* ws = (char*)d_ws;
    uint*  cnt = (uint*) (ws + WS_CNT);
    uint*  ptr = (uint*) (ws + WS_PTR);
    uint*  e1  = (uint*) (ws + WS_E1);
    uint2* e2  = (uint2*)(ws + WS_E2);

    // Build CSR (product-sorted reaction lists) every call — d_ws is re-poisoned.
    k_zero<<<(NCH * NSPEC + 255) / 256, 256, 0, stream>>>(cnt);
    k_hist<<<(RTOT + 255) / 256, 256, 0, stream>>>(inds_1p, inds_2p, cnt);
    k_scan<<<NCH, 256, 0, stream>>>(cnt, ptr);
    k_fill<<<(RTOT + 255) / 256, 256, 0, stream>>>(inds_1r, inds_1p, inds_2r, inds_2p,
                                                   cnt, e1, e2);
    k_main<<<BDIM, MBLOCK, 0, stream>>>(y_in, rates_1st, rates_2nd, ptr, e1, e2, y_out);
}